// Round 9
// baseline (115.202 us; speedup 1.0000x reference)
//
#include <hip/hip_runtime.h>
#include <math.h>

#define BB 4
#define CI 64
#define CO 64
#define HH 96
#define WW 96
#define HW (HH*WW)      // 9216
#define K2 9
#define PADC 1

// fused tiling: 4x4-px tiles
#define TW 4
#define TH 4
#define TPXT (TW*TH)        // 16 px per tile
#define TBX (WW/TW)         // 24
#define TBY (HH/TH)         // 24
#define NTILB (TBX*TBY)     // 576 tiles per batch
#define NTILES (BB*NTILB)   // 2304
#define GRID 512            // persistent: 2 blocks/CU, 9 tiles/CU balanced

// LDS window: rows [h0-4, h0+8], cols [w0-4, w0+11]
#define WR 13
#define WC 16
#define SREC 72             // ushorts per px record (144B -> 2-way LDS banks, free)
#define NSLOT (WR*WC)       // 208
#define STASKS (WR*32*4)    // 1664 staging tasks: r(13) x chp(32) x c4(4)

typedef __attribute__((ext_vector_type(8))) short short8;
typedef __attribute__((ext_vector_type(4))) float float4v;

// ws layout: Wf (18*64*32 ushort) + MWf (18*16*32 ushort)
#define WF_USHORTS (18*64*32)
#define MWF_USHORTS (18*16*32)

__device__ __forceinline__ float bf2f(short s) {
    return __uint_as_float(((unsigned int)(unsigned short)s) << 16);
}
__device__ __forceinline__ short f2bf(float f) {
    unsigned int u = __float_as_uint(f);
    u = (u + 0x7fffu + ((u >> 16) & 1u)) >> 16;   // RNE
    return (short)u;
}

// XCD swizzle: XCD g serves only batch g&3 so its 4MB L2 caches that batch's
// x slice. [R3: FETCH 15->4MB verified]. Stride-512 loop preserves g (512%8==0).
__device__ __forceinline__ void unswz(int tt, int* b, int* ty, int* tx) {
    int g = tt & 7, r = tt >> 3;        // r in [0,288)
    *b = g & 3;
    int tile = (g >> 2) * 288 + r;      // [0,576)
    *ty = tile / TBX; *tx = tile % TBX;
}

// ---------------- prep: weight pack only ----------------
__global__ __launch_bounds__(256) void pack_kernel(const float* __restrict__ wgt,
                                                   const float* __restrict__ mw,
                                                   unsigned short* __restrict__ Wf,
                                                   unsigned short* __restrict__ MWf) {
    int i = blockIdx.x * 256 + threadIdx.x;
    if (i < WF_USHORTS) {
        int frag = i >> 11;
        int o = (i >> 5) & 63;
        int tt = i & 31;
        int k = frag >> 1, cc = frag & 1;
        int c = cc * 32 + tt;
        Wf[i] = (unsigned short)f2bf(wgt[o * 576 + c * 9 + k]);
    } else if (i < WF_USHORTS + MWF_USHORTS) {
        int e = i - WF_USHORTS;
        int frag = e >> 9;
        int m = (e >> 5) & 15;
        int tt = e & 31;
        int q = frag >> 1, cc = frag & 1;
        int c = cc * 32 + tt;
        MWf[e] = (m < 9) ? (unsigned short)f2bf(mw[m * 576 + c * 9 + q]) : 0;
    }
}

// ---------------- fused: LDS window + register weights + persistent ----------
struct SmemT {
    unsigned short win[NSLOT * SREC];   // 29,952 B (part[3][16][64] aliases this)
    float mred[2][2][K2][TPXT];         // [ch][tg][tap][px]
    int   idx[K2][4][TPXT];
    float w[K2][4][TPXT];
};

template<int KB, int KE>
__device__ __forceinline__ void run_tiles(SmemT& sm, int t, int wv, int ch, int tg,
                                          const float* __restrict__ x,
                                          const float* __restrict__ off,
                                          const float* __restrict__ mbias,
                                          const unsigned short* __restrict__ Wf,
                                          const unsigned short* __restrict__ MWf,
                                          float* __restrict__ out, int bid) {
    constexpr int NK = KE - KB;
    int lane = t & 63;
    int n = lane & 15, quad = lane >> 4;
    float* part = (float*)sm.win;

    // ---- one-time: A-frags (main + mask) into registers [R7: verified win] ----
    short8 wA[NK][4];
    short8 mA[NK];
    #pragma unroll
    for (int kk = 0; kk < NK; kk++) {
        int k = KB + kk;
        const unsigned short* wp = Wf + (size_t)((k * 2 + ch) * 64) * 32 + quad * 8;
        #pragma unroll
        for (int s = 0; s < 4; s++)
            wA[kk][s] = *(const short8*)(wp + (s * 16 + n) * 32);
        mA[kk] = *(const short8*)(MWf + ((size_t)((k * 2 + ch) * 16 + n)) * 32 + quad * 8);
    }

    int ly = n >> 2, lx = n & 3;
    int cbase_us = ch * 32 + quad * 8;

    for (int tt = bid; tt < NTILES; tt += GRID) {
        int b, ty, tx; unswz(tt, &b, &ty, &tx);
        int h0 = ty * TH, w0 = tx * TW;
        int wr0 = h0 - 4, wc0 = w0 - 4;
        const float* xb = x + (size_t)b * CI * HW;
        int h = h0 + ly, wcc = w0 + lx;

        __syncthreads();   // prev iter's part reads done before win overwrite

        // ---- stage window: fp32 x -> bf16 LDS records (coalesced) ----
        for (int e = t; e < STASKS; e += 256) {
            int r = e >> 7;             // [0,13)
            int chp = (e >> 2) & 31;
            int c4 = e & 3;
            int row = min(max(wr0 + r, 0), HH - 1);
            int c0c = wc0 + c4 * 4;
            const float* s0 = xb + (size_t)(2 * chp) * HW + row * WW;
            const float* s1 = s0 + HW;
            float v0[4], v1[4];
            if (c0c >= 0 && c0c + 3 < WW) {
                float4v a = *(const float4v*)(s0 + c0c);
                float4v bq = *(const float4v*)(s1 + c0c);
                v0[0]=a[0]; v0[1]=a[1]; v0[2]=a[2]; v0[3]=a[3];
                v1[0]=bq[0]; v1[1]=bq[1]; v1[2]=bq[2]; v1[3]=bq[3];
            } else {
                #pragma unroll
                for (int j = 0; j < 4; j++) {
                    int cc2 = min(max(c0c + j, 0), WW - 1);
                    v0[j] = s0[cc2]; v1[j] = s1[cc2];
                }
            }
            #pragma unroll
            for (int j = 0; j < 4; j++) {
                unsigned int pk = (unsigned short)f2bf(v0[j]) |
                                  ((unsigned int)(unsigned short)f2bf(v1[j]) << 16);
                *(unsigned int*)&sm.win[(r * WC + c4 * 4 + j) * SREC + 2 * chp] = pk;
            }
        }
        __syncthreads();

        // ---- phase A: mask-conv partials via MFMA, B-frags from window ----
        {
            float4v macc = {0.f, 0.f, 0.f, 0.f};
            #pragma unroll
            for (int kk = 0; kk < NK; kk++) {
                int q = KB + kk;
                int hh = h + q / 3 - 1, ww2 = wcc + q % 3 - 1;
                bool valid = (hh >= 0) && (hh < HH) && (ww2 >= 0) && (ww2 < WW);
                short8 bfrag = {0, 0, 0, 0, 0, 0, 0, 0};
                if (valid) {
                    int slot = (hh - wr0) * WC + (ww2 - wc0);
                    bfrag = *(const short8*)&sm.win[slot * SREC + cbase_us];
                }
                macc = __builtin_amdgcn_mfma_f32_16x16x32_bf16(mA[kk], bfrag, macc, 0, 0, 0);
            }
            #pragma unroll
            for (int r = 0; r < 4; r++) {
                int row = quad * 4 + r;
                if (row < 9) sm.mred[ch][tg][row][n] = macc[r];
            }
        }
        __syncthreads();

        // ---- phase B: sampling metadata (mask folded into bilinear wts) ----
        if (t < K2 * TPXT) {
            int k = t >> 4, pe = t & 15;
            int ph = h0 + (pe >> 2), pw = w0 + (pe & 3);
            int p = ph * WW + pw;
            float oy = off[((size_t)b * 2 * K2 + 2 * k) * HW + p];
            float ox = off[((size_t)b * 2 * K2 + 2 * k + 1) * HW + p];
            float s = sm.mred[0][0][k][pe] + sm.mred[0][1][k][pe] +
                      sm.mred[1][0][k][pe] + sm.mred[1][1][k][pe] + mbias[k];
            float m = 1.f / (1.f + expf(-s));
            float py  = (float)(ph - PADC + k / 3) + oy;
            float pxf = (float)(pw - PADC + k % 3) + ox;
            float y0f = floorf(py), x0f = floorf(pxf);
            float wy = py - y0f, wx = pxf - x0f;
            int y0 = (int)y0f, x0 = (int)x0f;
            int y1 = y0 + 1, x1 = x0 + 1;
            int y0c = min(max(y0, 0), HH - 1), y1c = min(max(y1, 0), HH - 1);
            int x0c = min(max(x0, 0), WW - 1), x1c = min(max(x1, 0), WW - 1);
            bool vy0 = (y0 >= 0) && (y0 < HH), vy1 = (y1 >= 0) && (y1 < HH);
            bool vx0 = (x0 >= 0) && (x0 < WW), vx1 = (x1 >= 0) && (x1 < WW);
            float w00 = (1.f - wy) * (1.f - wx) * m; if (!(vy0 && vx0)) w00 = 0.f;
            float w01 = (1.f - wy) * wx * m;         if (!(vy0 && vx1)) w01 = 0.f;
            float w10 = wy * (1.f - wx) * m;         if (!(vy1 && vx0)) w10 = 0.f;
            float w11 = wy * wx * m;                 if (!(vy1 && vx1)) w11 = 0.f;
            sm.idx[k][0][pe] = (y0c << 16) | x0c;
            sm.idx[k][1][pe] = (y0c << 16) | x1c;
            sm.idx[k][2][pe] = (y1c << 16) | x0c;
            sm.idx[k][3][pe] = (y1c << 16) | x1c;
            sm.w[k][0][pe] = w00; sm.w[k][1][pe] = w01;
            sm.w[k][2][pe] = w10; sm.w[k][3][pe] = w11;
        }
        __syncthreads();

        // ---- phase C: gather from window (rare global fallback) + MFMA ----
        float4v acc0 = {0.f, 0.f, 0.f, 0.f};
        float4v acc1 = {0.f, 0.f, 0.f, 0.f};
        float4v acc2 = {0.f, 0.f, 0.f, 0.f};
        float4v acc3 = {0.f, 0.f, 0.f, 0.f};
        const float* xfb = xb + (size_t)(ch * 32 + quad * 8) * HW;

        #pragma unroll
        for (int kk = 0; kk < NK; kk++) {
            int k = KB + kk;
            short8 U[4];
            #pragma unroll
            for (int cor = 0; cor < 4; cor++) {
                int yx = sm.idx[k][cor][n];
                int yy = yx >> 16, xx = yx & 0xffff;
                int r = yy - wr0, c = xx - wc0;
                bool inw = ((unsigned)r < (unsigned)WR) && ((unsigned)c < (unsigned)WC);
                short8 u;
                if (inw) {
                    u = *(const short8*)&sm.win[(r * WC + c) * SREC + cbase_us];
                } else {
                    const float* fs = xfb + yy * WW + xx;
                    #pragma unroll
                    for (int j = 0; j < 8; j++) u[j] = f2bf(fs[(size_t)j * HW]);
                }
                U[cor] = u;
            }
            float w0 = sm.w[k][0][n], w1 = sm.w[k][1][n];
            float w2 = sm.w[k][2][n], w3 = sm.w[k][3][n];
            short8 bfrag;
            #pragma unroll
            for (int j = 0; j < 8; j++) {
                float v = bf2f(U[0][j]) * w0 + bf2f(U[1][j]) * w1 +
                          bf2f(U[2][j]) * w2 + bf2f(U[3][j]) * w3;
                bfrag[j] = f2bf(v);
            }
            acc0 = __builtin_amdgcn_mfma_f32_16x16x32_bf16(wA[kk][0], bfrag, acc0, 0, 0, 0);
            acc1 = __builtin_amdgcn_mfma_f32_16x16x32_bf16(wA[kk][1], bfrag, acc1, 0, 0, 0);
            acc2 = __builtin_amdgcn_mfma_f32_16x16x32_bf16(wA[kk][2], bfrag, acc2, 0, 0, 0);
            acc3 = __builtin_amdgcn_mfma_f32_16x16x32_bf16(wA[kk][3], bfrag, acc3, 0, 0, 0);
        }

        // ---- cross-wave reduce via part (aliases dead window) + epilogue ----
        __syncthreads();   // window reads done before alias write
        if (wv != 0) {
            #pragma unroll
            for (int r = 0; r < 4; r++) {
                part[((wv - 1) * 16 + 0 * 4 + r) * 64 + lane] = acc0[r];
                part[((wv - 1) * 16 + 1 * 4 + r) * 64 + lane] = acc1[r];
                part[((wv - 1) * 16 + 2 * 4 + r) * 64 + lane] = acc2[r];
                part[((wv - 1) * 16 + 3 * 4 + r) * 64 + lane] = acc3[r];
            }
        }
        __syncthreads();
        if (wv == 0) {
            float* ob = out + (size_t)b * CO * HW + h * WW + wcc;
            #pragma unroll
            for (int r = 0; r < 4; r++) {
                int j0 = r, j1 = 4 + r, j2 = 8 + r, j3 = 12 + r;
                ob[(size_t)(0 * 16 + quad * 4 + r) * HW] = acc0[r] +
                    part[j0 * 64 + lane] + part[(16 + j0) * 64 + lane] + part[(32 + j0) * 64 + lane];
                ob[(size_t)(1 * 16 + quad * 4 + r) * HW] = acc1[r] +
                    part[j1 * 64 + lane] + part[(16 + j1) * 64 + lane] + part[(32 + j1) * 64 + lane];
                ob[(size_t)(2 * 16 + quad * 4 + r) * HW] = acc2[r] +
                    part[j2 * 64 + lane] + part[(16 + j2) * 64 + lane] + part[(32 + j2) * 64 + lane];
                ob[(size_t)(3 * 16 + quad * 4 + r) * HW] = acc3[r] +
                    part[j3 * 64 + lane] + part[(16 + j3) * 64 + lane] + part[(32 + j3) * 64 + lane];
            }
        }
    }
}

__global__ __launch_bounds__(256, 2) void fused_kernel(const float* __restrict__ x,
                                                       const float* __restrict__ off,
                                                       const float* __restrict__ mbias,
                                                       const unsigned short* __restrict__ Wf,
                                                       const unsigned short* __restrict__ MWf,
                                                       float* __restrict__ out) {
    __shared__ SmemT sm;
    int t = threadIdx.x;
    int wv = t >> 6;
    int ch = wv & 1, tg = wv >> 1;
    if (tg == 0)
        run_tiles<0, 5>(sm, t, wv, ch, tg, x, off, mbias, Wf, MWf, out, blockIdx.x);
    else
        run_tiles<5, 9>(sm, t, wv, ch, tg, x, off, mbias, Wf, MWf, out, blockIdx.x);
}

extern "C" void kernel_launch(void* const* d_in, const int* in_sizes, int n_in,
                              void* d_out, int out_size, void* d_ws, size_t ws_size,
                              hipStream_t stream) {
    const float* x   = (const float*)d_in[0];
    const float* off = (const float*)d_in[1];
    const float* wgt = (const float*)d_in[2];
    const float* mw  = (const float*)d_in[3];
    const float* mb  = (const float*)d_in[4];
    float* out = (float*)d_out;

    unsigned short* Wf  = (unsigned short*)d_ws;
    unsigned short* MWf = Wf + WF_USHORTS;

    hipLaunchKernelGGL(pack_kernel, dim3((WF_USHORTS + MWF_USHORTS + 255) / 256), dim3(256),
                       0, stream, wgt, mw, Wf, MWf);
    hipLaunchKernelGGL(fused_kernel, dim3(GRID), dim3(256), 0, stream,
                       x, off, mb, Wf, MWf, out);
}

// Round 10
// 106.799 us; speedup vs baseline: 1.0787x; 1.0787x over previous
//
#include <hip/hip_runtime.h>
#include <math.h>

#define BB 4
#define CI 64
#define CO 64
#define HH 96
#define WW 96
#define HW (HH*WW)      // 9216
#define K2 9
#define PADC 1

// 4x4-px tiles, vertical strips per block
#define TW 4
#define TH 4
#define TPXT 16
#define TBX (WW/TW)         // 24 tile-cols
#define TBY (HH/TH)         // 24 tile-rows
#define NTILES (BB*TBX*TBY) // 2304
#define GRID 480            // 96 columns x 5 strips (len 5,5,5,5,4)

// LDS ring window: 16 rows x 16 cols, record stride 70 ushorts (35 dwords, odd)
#define WC 16
#define SREC 70
#define RING 16
#define NSLOT (RING*WC)     // 256

typedef __attribute__((ext_vector_type(8))) short short8;
typedef __attribute__((ext_vector_type(4))) float float4v;

#define WF_USHORTS (18*64*32)
#define MWF_USHORTS (18*16*32)

__device__ __forceinline__ float bf2f(short s) {
    return __uint_as_float(((unsigned int)(unsigned short)s) << 16);
}
__device__ __forceinline__ short f2bf(float f) {
    unsigned int u = __float_as_uint(f);
    u = (u + 0x7fffu + ((u >> 16) & 1u)) >> 16;   // RNE
    return (short)u;
}

// ---------------- prep: weight pack only ----------------
__global__ __launch_bounds__(256) void pack_kernel(const float* __restrict__ wgt,
                                                   const float* __restrict__ mw,
                                                   unsigned short* __restrict__ Wf,
                                                   unsigned short* __restrict__ MWf) {
    int i = blockIdx.x * 256 + threadIdx.x;
    if (i < WF_USHORTS) {
        int frag = i >> 11;
        int o = (i >> 5) & 63;
        int tt = i & 31;
        int k = frag >> 1, cc = frag & 1;
        int c = cc * 32 + tt;
        Wf[i] = (unsigned short)f2bf(wgt[o * 576 + c * 9 + k]);
    } else if (i < WF_USHORTS + MWF_USHORTS) {
        int e = i - WF_USHORTS;
        int frag = e >> 9;
        int m = (e >> 5) & 15;
        int tt = e & 31;
        int q = frag >> 1, cc = frag & 1;
        int c = cc * 32 + tt;
        MWf[e] = (m < 9) ? (unsigned short)f2bf(mw[m * 576 + c * 9 + q]) : 0;
    }
}

// ---------------- fused ----------------
struct SmemT {
    unsigned short win[NSLOT * SREC];   // 35,840 B  (ring window, LIVE across tiles)
    float mred[2][2][K2][TPXT];         // 2,304 B
    int   idx[K2][4][TPXT];             // 2,304 B
    float w[K2][4][TPXT];               // 2,304 B
    float part[3][16][64];              // 12,288 B
};                                      // total 55,040 B -> 2 blocks/CU

__device__ __forceinline__ short8 ld_win(const unsigned int* w32, int dw) {
    union { unsigned int u[4]; short8 s; } z;
    z.u[0] = w32[dw + 0];
    z.u[1] = w32[dw + 1];
    z.u[2] = w32[dw + 2];
    z.u[3] = w32[dw + 3];
    return z.s;
}

// stage rows [rs0, rs0+nr) (labels; data row-clamped) into the ring
__device__ __forceinline__ void stage_rows(unsigned int* w32, int t, int rs0, int nr,
                                           int wc0, const float* __restrict__ xb) {
    int ntask = nr * 128;               // nr rows x 32 ch-pairs x 4 col-chunks
    for (int e = t; e < ntask; e += 256) {
        int ri = e >> 7;
        int chp = (e >> 2) & 31;
        int c4 = e & 3;
        int label = rs0 + ri;
        int row = min(max(label, 0), HH - 1);
        int rslot = (label & 15) * WC;
        int c0c = wc0 + c4 * 4;
        const float* s0 = xb + (size_t)(2 * chp) * HW + row * WW;
        const float* s1 = s0 + HW;
        float v0[4], v1[4];
        if (c0c >= 0 && c0c + 3 < WW) {
            float4v a = *(const float4v*)(s0 + c0c);
            float4v bq = *(const float4v*)(s1 + c0c);
            v0[0]=a[0]; v0[1]=a[1]; v0[2]=a[2]; v0[3]=a[3];
            v1[0]=bq[0]; v1[1]=bq[1]; v1[2]=bq[2]; v1[3]=bq[3];
        } else {
            #pragma unroll
            for (int j = 0; j < 4; j++) {
                int cc2 = min(max(c0c + j, 0), WW - 1);
                v0[j] = s0[cc2]; v1[j] = s1[cc2];
            }
        }
        #pragma unroll
        for (int j = 0; j < 4; j++) {
            unsigned int pk = (unsigned short)f2bf(v0[j]) |
                              ((unsigned int)(unsigned short)f2bf(v1[j]) << 16);
            w32[(rslot + c4 * 4 + j) * 35 + chp] = pk;   // dword chp = channels 2chp,2chp+1
        }
    }
}

template<int KB, int KE>
__device__ __forceinline__ void run_strip(SmemT& sm, int t, int wv, int ch, int tg,
                                          const float* __restrict__ x,
                                          const float* __restrict__ off,
                                          const float* __restrict__ mbias,
                                          const unsigned short* __restrict__ Wf,
                                          const unsigned short* __restrict__ MWf,
                                          float* __restrict__ out, int bid) {
    constexpr int NK = KE - KB;
    int lane = t & 63;
    int n = lane & 15, quad = lane >> 4;
    unsigned int* w32 = (unsigned int*)sm.win;
    const unsigned int* w32c = (const unsigned int*)sm.win;

    // strip decode: g -> (batch, tx-half) for XCD-L2 affinity [R3 verified]
    int g = bid & 7, r = bid >> 3;      // r in [0,60)
    int b = g & 3, txh = g >> 2;
    int col = r / 5, s = r % 5;
    int tx = txh * 12 + col;
    int ty0 = (s < 4) ? s * 5 : 20;
    int len = (s < 4) ? 5 : 4;
    int w0 = tx * TW;
    int wc0 = w0 - 4;
    const float* xb = x + (size_t)b * CI * HW;

    // ---- one-time register A-frags [R7 verified] ----
    short8 wA[NK][4];
    short8 mA[NK];
    #pragma unroll
    for (int kk = 0; kk < NK; kk++) {
        int k = KB + kk;
        const unsigned short* wp = Wf + (size_t)((k * 2 + ch) * 64) * 32 + quad * 8;
        #pragma unroll
        for (int ss = 0; ss < 4; ss++)
            wA[kk][ss] = *(const short8*)(wp + (ss * 16 + n) * 32);
        mA[kk] = *(const short8*)(MWf + ((size_t)((k * 2 + ch) * 16 + n)) * 32 + quad * 8);
    }

    int ly = n >> 2, lx = n & 3;
    int cbase_dw = ch * 16 + quad * 4;   // dword offset within record

    for (int j = 0; j < len; j++) {
        int ty = ty0 + j;
        int h0 = ty * TH;
        int h = h0 + ly, wcc = w0 + lx;

        // ---- stage: full window first tile, 4 new rows after ----
        if (j == 0) stage_rows(w32, t, h0 - 4, 13, wc0, xb);
        else        stage_rows(w32, t, h0 + 5, 4, wc0, xb);
        __syncthreads();

        // ---- phase A: mask-conv partials (conflict-free b32 window reads) ----
        {
            float4v macc = {0.f, 0.f, 0.f, 0.f};
            #pragma unroll
            for (int kk = 0; kk < NK; kk++) {
                int q = KB + kk;
                int hh = h + q / 3 - 1, ww2 = wcc + q % 3 - 1;
                bool valid = (hh >= 0) && (hh < HH) && (ww2 >= 0) && (ww2 < WW);
                short8 bfrag = {0, 0, 0, 0, 0, 0, 0, 0};
                if (valid) {
                    int slot = (hh & 15) * WC + (ww2 - wc0);
                    bfrag = ld_win(w32c, slot * 35 + cbase_dw);
                }
                macc = __builtin_amdgcn_mfma_f32_16x16x32_bf16(mA[kk], bfrag, macc, 0, 0, 0);
            }
            #pragma unroll
            for (int rr = 0; rr < 4; rr++) {
                int row = quad * 4 + rr;
                if (row < 9) sm.mred[ch][tg][row][n] = macc[rr];
            }
        }
        __syncthreads();

        // ---- phase B: sampling metadata ----
        if (t < K2 * TPXT) {
            int k = t >> 4, pe = t & 15;
            int ph = h0 + (pe >> 2), pw = w0 + (pe & 3);
            int p = ph * WW + pw;
            float oy = off[((size_t)b * 2 * K2 + 2 * k) * HW + p];
            float ox = off[((size_t)b * 2 * K2 + 2 * k + 1) * HW + p];
            float sl = sm.mred[0][0][k][pe] + sm.mred[0][1][k][pe] +
                       sm.mred[1][0][k][pe] + sm.mred[1][1][k][pe] + mbias[k];
            float m = 1.f / (1.f + expf(-sl));
            float py  = (float)(ph - PADC + k / 3) + oy;
            float pxf = (float)(pw - PADC + k % 3) + ox;
            float y0f = floorf(py), x0f = floorf(pxf);
            float wy = py - y0f, wx = pxf - x0f;
            int y0 = (int)y0f, x0 = (int)x0f;
            int y1 = y0 + 1, x1 = x0 + 1;
            int y0c = min(max(y0, 0), HH - 1), y1c = min(max(y1, 0), HH - 1);
            int x0c = min(max(x0, 0), WW - 1), x1c = min(max(x1, 0), WW - 1);
            bool vy0 = (y0 >= 0) && (y0 < HH), vy1 = (y1 >= 0) && (y1 < HH);
            bool vx0 = (x0 >= 0) && (x0 < WW), vx1 = (x1 >= 0) && (x1 < WW);
            float w00 = (1.f - wy) * (1.f - wx) * m; if (!(vy0 && vx0)) w00 = 0.f;
            float w01 = (1.f - wy) * wx * m;         if (!(vy0 && vx1)) w01 = 0.f;
            float w10 = wy * (1.f - wx) * m;         if (!(vy1 && vx0)) w10 = 0.f;
            float w11 = wy * wx * m;                 if (!(vy1 && vx1)) w11 = 0.f;
            sm.idx[k][0][pe] = (y0c << 16) | x0c;
            sm.idx[k][1][pe] = (y0c << 16) | x1c;
            sm.idx[k][2][pe] = (y1c << 16) | x0c;
            sm.idx[k][3][pe] = (y1c << 16) | x1c;
            sm.w[k][0][pe] = w00; sm.w[k][1][pe] = w01;
            sm.w[k][2][pe] = w10; sm.w[k][3][pe] = w11;
        }
        __syncthreads();

        // ---- phase C: conflict-free window gathers + blend + MFMA ----
        float4v acc0 = {0.f, 0.f, 0.f, 0.f};
        float4v acc1 = {0.f, 0.f, 0.f, 0.f};
        float4v acc2 = {0.f, 0.f, 0.f, 0.f};
        float4v acc3 = {0.f, 0.f, 0.f, 0.f};
        const float* xfb = xb + (size_t)(ch * 32 + quad * 8) * HW;

        #pragma unroll
        for (int kk = 0; kk < NK; kk++) {
            int k = KB + kk;
            short8 U[4];
            #pragma unroll
            for (int cor = 0; cor < 4; cor++) {
                int yx = sm.idx[k][cor][n];
                int yy = yx >> 16, xx = yx & 0xffff;
                bool inw = (yy >= h0 - 4) && (yy <= h0 + 8) &&
                           (xx >= wc0) && (xx <= wc0 + 15);
                short8 u;
                if (inw) {
                    int slot = (yy & 15) * WC + (xx - wc0);
                    u = ld_win(w32c, slot * 35 + cbase_dw);
                } else {
                    const float* fs = xfb + yy * WW + xx;
                    #pragma unroll
                    for (int jj = 0; jj < 8; jj++) u[jj] = f2bf(fs[(size_t)jj * HW]);
                }
                U[cor] = u;
            }
            float w0v = sm.w[k][0][n], w1v = sm.w[k][1][n];
            float w2v = sm.w[k][2][n], w3v = sm.w[k][3][n];
            short8 bfrag;
            #pragma unroll
            for (int jj = 0; jj < 8; jj++) {
                float v = bf2f(U[0][jj]) * w0v + bf2f(U[1][jj]) * w1v +
                          bf2f(U[2][jj]) * w2v + bf2f(U[3][jj]) * w3v;
                bfrag[jj] = f2bf(v);
            }
            acc0 = __builtin_amdgcn_mfma_f32_16x16x32_bf16(wA[kk][0], bfrag, acc0, 0, 0, 0);
            acc1 = __builtin_amdgcn_mfma_f32_16x16x32_bf16(wA[kk][1], bfrag, acc1, 0, 0, 0);
            acc2 = __builtin_amdgcn_mfma_f32_16x16x32_bf16(wA[kk][2], bfrag, acc2, 0, 0, 0);
            acc3 = __builtin_amdgcn_mfma_f32_16x16x32_bf16(wA[kk][3], bfrag, acc3, 0, 0, 0);
        }

        // ---- cross-wave reduce (part is its own LDS; ring stays live) ----
        if (wv != 0) {
            #pragma unroll
            for (int rr = 0; rr < 4; rr++) {
                sm.part[wv - 1][0 * 4 + rr][lane] = acc0[rr];
                sm.part[wv - 1][1 * 4 + rr][lane] = acc1[rr];
                sm.part[wv - 1][2 * 4 + rr][lane] = acc2[rr];
                sm.part[wv - 1][3 * 4 + rr][lane] = acc3[rr];
            }
        }
        __syncthreads();
        if (wv == 0) {
            float* ob = out + (size_t)b * CO * HW + h * WW + wcc;
            #pragma unroll
            for (int rr = 0; rr < 4; rr++) {
                int j0 = rr, j1 = 4 + rr, j2 = 8 + rr, j3 = 12 + rr;
                ob[(size_t)(0 * 16 + quad * 4 + rr) * HW] = acc0[rr] +
                    sm.part[0][j0][lane] + sm.part[1][j0][lane] + sm.part[2][j0][lane];
                ob[(size_t)(1 * 16 + quad * 4 + rr) * HW] = acc1[rr] +
                    sm.part[0][j1][lane] + sm.part[1][j1][lane] + sm.part[2][j1][lane];
                ob[(size_t)(2 * 16 + quad * 4 + rr) * HW] = acc2[rr] +
                    sm.part[0][j2][lane] + sm.part[1][j2][lane] + sm.part[2][j2][lane];
                ob[(size_t)(3 * 16 + quad * 4 + rr) * HW] = acc3[rr] +
                    sm.part[0][j3][lane] + sm.part[1][j3][lane] + sm.part[2][j3][lane];
            }
        }
        __syncthreads();   // part reads done before next tile reuses it
    }
}

__global__ __launch_bounds__(256, 2) void fused_kernel(const float* __restrict__ x,
                                                       const float* __restrict__ off,
                                                       const float* __restrict__ mbias,
                                                       const unsigned short* __restrict__ Wf,
                                                       const unsigned short* __restrict__ MWf,
                                                       float* __restrict__ out) {
    __shared__ SmemT sm;
    int t = threadIdx.x;
    int wv = t >> 6;
    int ch = wv & 1, tg = wv >> 1;
    if (tg == 0)
        run_strip<0, 5>(sm, t, wv, ch, tg, x, off, mbias, Wf, MWf, out, blockIdx.x);
    else
        run_strip<5, 9>(sm, t, wv, ch, tg, x, off, mbias, Wf, MWf, out, blockIdx.x);
}

extern "C" void kernel_launch(void* const* d_in, const int* in_sizes, int n_in,
                              void* d_out, int out_size, void* d_ws, size_t ws_size,
                              hipStream_t stream) {
    const float* x   = (const float*)d_in[0];
    const float* off = (const float*)d_in[1];
    const float* wgt = (const float*)d_in[2];
    const float* mw  = (const float*)d_in[3];
    const float* mb  = (const float*)d_in[4];
    float* out = (float*)d_out;

    unsigned short* Wf  = (unsigned short*)d_ws;
    unsigned short* MWf = Wf + WF_USHORTS;

    hipLaunchKernelGGL(pack_kernel, dim3((WF_USHORTS + MWF_USHORTS + 255) / 256), dim3(256),
                       0, stream, wgt, mw, Wf, MWf);
    hipLaunchKernelGGL(fused_kernel, dim3(GRID), dim3(256), 0, stream,
                       x, off, mb, Wf, MWf, out);
}